// Round 3
// baseline (236.841 us; speedup 1.0000x reference)
//
#include <hip/hip_runtime.h>
#include <hip/hip_cooperative_groups.h>
#include <math.h>

namespace cg = cooperative_groups;

#define H 1024
#define V 50257
#define NB 1024          // cooperative grid: 1024 blocks x 256 thr (4 blocks/CU)
#define NB_TILES 3142    // ceil(V / 16)
#define NB_FINAL 64

__device__ __forceinline__ float wave_reduce_sum(float v) {
#pragma unroll
    for (int off = 32; off >= 1; off >>= 1)
        v += __shfl_xor(v, off, 64);
    return v;
}

// online softmax merge: (m,s) <- merge((m,s),(mi,si))
__device__ __forceinline__ void sm_merge(float& m, float& s, float mi, float si) {
    if (mi > m) {
        s = s * expf(m - mi) + si;   // m==-inf, s==0 -> si
        m = mi;
    } else if (si > 0.f) {
        s += si * expf(mi - m);
    }
}

// ---------------- fused cooperative kernel ----------------
// phase 1: block j computes the 6 dot products for hidden index j -> h_new[j]
// phase 2: grid-strided tiles of 16 W_out rows (4 rows/wave), logits -> out,
//          per-block online-softmax partials -> pmax/psum[bid]
// phase 3: every block merges all NB partials in identical order
//          (bit-identical total), subtracts in place.
__global__ __launch_bounds__(256, 4) void decoder_fused(
    const int* __restrict__ ids, const float* __restrict__ emb,
    const float* __restrict__ hidden,
    const float* __restrict__ W_ih, const float* __restrict__ W_hh,
    const float* __restrict__ b_ih, const float* __restrict__ b_hh,
    const float* __restrict__ W_out, const float* __restrict__ b_out,
    float* __restrict__ out, float* __restrict__ hnew,
    float* __restrict__ pmax, float* __restrict__ psum)
{
    cg::grid_group grid = cg::this_grid();
    const int bid  = blockIdx.x;
    const int t    = threadIdx.x;
    const int wave = t >> 6;
    const int lane = t & 63;

    __shared__ float red[4][6];
    __shared__ float wm[4], wsv[4];
    __shared__ float total_s;

    // ---------- phase 1: GRU ----------
    {
        const int j = bid;                 // 0..H-1
        const int id = ids[0];
        const float4* xr = (const float4*)(emb + (size_t)id * H);
        const float4* hr = (const float4*)hidden;

        float4 x4 = xr[t];
        x4.x = fmaxf(x4.x, 0.f); x4.y = fmaxf(x4.y, 0.f);
        x4.z = fmaxf(x4.z, 0.f); x4.w = fmaxf(x4.w, 0.f);
        const float4 h4 = hr[t];

        float acc[6];
#pragma unroll
        for (int g = 0; g < 3; ++g) {
            const size_t row = (size_t)g * H + j;
            const float4 wi4 = ((const float4*)(W_ih + row * H))[t];
            const float4 wh4 = ((const float4*)(W_hh + row * H))[t];
            acc[2*g]   = wi4.x * x4.x + wi4.y * x4.y + wi4.z * x4.z + wi4.w * x4.w;
            acc[2*g+1] = wh4.x * h4.x + wh4.y * h4.y + wh4.z * h4.z + wh4.w * h4.w;
        }
#pragma unroll
        for (int g = 0; g < 6; ++g) acc[g] = wave_reduce_sum(acc[g]);
        if (lane == 0) {
#pragma unroll
            for (int g = 0; g < 6; ++g) red[wave][g] = acc[g];
        }
        __syncthreads();
        if (t == 0) {
            float tt[6];
#pragma unroll
            for (int g = 0; g < 6; ++g)
                tt[g] = red[0][g] + red[1][g] + red[2][g] + red[3][g];
            const float ir  = tt[0] + b_ih[j],        hr_ = tt[1] + b_hh[j];
            const float iz  = tt[2] + b_ih[H + j],    hz  = tt[3] + b_hh[H + j];
            const float in_ = tt[4] + b_ih[2*H + j],  hn  = tt[5] + b_hh[2*H + j];
            const float r = 1.f / (1.f + expf(-(ir + hr_)));
            const float z = 1.f / (1.f + expf(-(iz + hz)));
            const float n = tanhf(in_ + r * hn);
            const float h = hidden[j];
            const float o = (1.f - z) * n + z * h;
            hnew[j] = o;
            out[V + j] = o;
        }
    }
    grid.sync();

    // ---------- phase 2: logits + per-block softmax partials ----------
    {
        // h_new held in registers: thread uses the same 4 float4 for every row
        float4 hreg[4];
#pragma unroll
        for (int it = 0; it < 4; ++it)
            hreg[it] = ((const float4*)hnew)[it * 64 + lane];

        float m = -INFINITY, s = 0.f;
        for (int tile = bid; tile < NB_TILES; tile += NB) {
            const int base = tile * 16 + wave * 4;
#pragma unroll
            for (int r = 0; r < 4; ++r) {
                const int row = base + r;
                if (row >= V) continue;           // only last tile, wave-uniform
                const float4* w = (const float4*)(W_out + (size_t)row * H);
                float acc = 0.f;
#pragma unroll
                for (int it = 0; it < 4; ++it) {
                    const float4 w4 = w[it * 64 + lane];
                    acc += w4.x * hreg[it].x + w4.y * hreg[it].y
                         + w4.z * hreg[it].z + w4.w * hreg[it].w;
                }
                acc = wave_reduce_sum(acc);
                if (lane == 0) {
                    const float logit = acc + b_out[row];
                    out[row] = logit;
                    sm_merge(m, s, logit, 1.f);
                }
            }
        }
        if (lane == 0) { wm[wave] = m; wsv[wave] = s; }
        __syncthreads();
        if (t == 0) {
            float M = wm[0], S = wsv[0];
#pragma unroll
            for (int w2 = 1; w2 < 4; ++w2) sm_merge(M, S, wm[w2], wsv[w2]);
            pmax[bid] = M;
            psum[bid] = S;
        }
    }
    grid.sync();

    // ---------- phase 3: redundant deterministic merge + subtract ----------
    {
        float m = -INFINITY, s = 0.f;
        for (int i = t; i < NB; i += 256)
            sm_merge(m, s, pmax[i], psum[i]);
#pragma unroll
        for (int off = 32; off >= 1; off >>= 1) {
            const float mo = __shfl_xor(m, off, 64);
            const float so = __shfl_xor(s, off, 64);
            sm_merge(m, s, mo, so);
        }
        if (lane == 0) { wm[wave] = m; wsv[wave] = s; }
        __syncthreads();
        if (t == 0) {
            float M = wm[0], S = wsv[0];
#pragma unroll
            for (int w2 = 1; w2 < 4; ++w2) sm_merge(M, S, wm[w2], wsv[w2]);
            total_s = M + logf(S);
        }
        __syncthreads();
        const float tot = total_s;
        const int v = bid * 256 + t;              // NB*256 = 262144 >= V
        if (v < V) out[v] -= tot;
    }
}

// ---------------- fallback path (proven round-2 kernels) ----------------
__global__ __launch_bounds__(256) void gru_fused_kernel(
    const int* __restrict__ ids, const float* __restrict__ emb,
    const float* __restrict__ hidden,
    const float* __restrict__ W_ih, const float* __restrict__ W_hh,
    const float* __restrict__ b_ih, const float* __restrict__ b_hh,
    float* __restrict__ hnew, float* __restrict__ out_hidden)
{
    const int j = blockIdx.x;
    const int t = threadIdx.x;
    const int wave = t >> 6;
    const int lane = t & 63;

    const int id = ids[0];
    const float4* xr = (const float4*)(emb + (size_t)id * H);
    const float4* hr = (const float4*)hidden;

    float4 x4 = xr[t];
    x4.x = fmaxf(x4.x, 0.f); x4.y = fmaxf(x4.y, 0.f);
    x4.z = fmaxf(x4.z, 0.f); x4.w = fmaxf(x4.w, 0.f);
    const float4 h4 = hr[t];

    float acc[6];
#pragma unroll
    for (int g = 0; g < 3; ++g) {
        const size_t row = (size_t)g * H + j;
        const float4 wi4 = ((const float4*)(W_ih + row * H))[t];
        const float4 wh4 = ((const float4*)(W_hh + row * H))[t];
        acc[2*g]   = wi4.x * x4.x + wi4.y * x4.y + wi4.z * x4.z + wi4.w * x4.w;
        acc[2*g+1] = wh4.x * h4.x + wh4.y * h4.y + wh4.z * h4.z + wh4.w * h4.w;
    }
#pragma unroll
    for (int g = 0; g < 6; ++g) acc[g] = wave_reduce_sum(acc[g]);

    __shared__ float red[4][6];
    if (lane == 0) {
#pragma unroll
        for (int g = 0; g < 6; ++g) red[wave][g] = acc[g];
    }
    __syncthreads();
    if (t == 0) {
        float tt[6];
#pragma unroll
        for (int g = 0; g < 6; ++g)
            tt[g] = red[0][g] + red[1][g] + red[2][g] + red[3][g];
        const float ir  = tt[0] + b_ih[j],        hr_ = tt[1] + b_hh[j];
        const float iz  = tt[2] + b_ih[H + j],    hz  = tt[3] + b_hh[H + j];
        const float in_ = tt[4] + b_ih[2*H + j],  hn  = tt[5] + b_hh[2*H + j];
        const float r = 1.f / (1.f + expf(-(ir + hr_)));
        const float z = 1.f / (1.f + expf(-(iz + hz)));
        const float n = tanhf(in_ + r * hn);
        const float h = hidden[j];
        const float o = (1.f - z) * n + z * h;
        hnew[j] = o;
        out_hidden[j] = o;
    }
}

__global__ __launch_bounds__(256) void logits_kernel(
    const float* __restrict__ hnew, const float* __restrict__ W_out,
    const float* __restrict__ b_out, float* __restrict__ logits,
    float* __restrict__ pmax, float* __restrict__ psum)
{
    __shared__ float wm[4], wsv[4];
    const int wave = threadIdx.x >> 6;
    const int lane = threadIdx.x & 63;
    const int base = blockIdx.x * 16 + wave * 4;

    float4 hreg[4];
#pragma unroll
    for (int it = 0; it < 4; ++it)
        hreg[it] = ((const float4*)hnew)[it * 64 + lane];

    float m = -INFINITY, s = 0.f;
#pragma unroll
    for (int r = 0; r < 4; ++r) {
        const int row = base + r;
        if (row >= V) continue;
        const float4* w = (const float4*)(W_out + (size_t)row * H);
        float acc = 0.f;
#pragma unroll
        for (int it = 0; it < 4; ++it) {
            const float4 w4 = w[it * 64 + lane];
            acc += w4.x * hreg[it].x + w4.y * hreg[it].y
                 + w4.z * hreg[it].z + w4.w * hreg[it].w;
        }
        acc = wave_reduce_sum(acc);
        if (lane == 0) {
            const float logit = acc + b_out[row];
            logits[row] = logit;
            sm_merge(m, s, logit, 1.f);
        }
    }
    if (lane == 0) { wm[wave] = m; wsv[wave] = s; }
    __syncthreads();
    if (threadIdx.x == 0) {
        float M = wm[0], S = wsv[0];
#pragma unroll
        for (int w2 = 1; w2 < 4; ++w2) sm_merge(M, S, wm[w2], wsv[w2]);
        pmax[blockIdx.x] = M;
        psum[blockIdx.x] = S;
    }
}

__global__ __launch_bounds__(256) void finalize_kernel(
    const float* __restrict__ pmax, const float* __restrict__ psum,
    float* __restrict__ out)
{
    __shared__ float wm[4], wsv[4];
    __shared__ float total_s;
    const int tid = threadIdx.x;

    float m = -INFINITY, s = 0.f;
    for (int i = tid; i < NB_TILES; i += 256)
        sm_merge(m, s, pmax[i], psum[i]);
#pragma unroll
    for (int off = 32; off >= 1; off >>= 1) {
        const float mo = __shfl_xor(m, off, 64);
        const float so = __shfl_xor(s, off, 64);
        sm_merge(m, s, mo, so);
    }
    if ((tid & 63) == 0) { wm[tid >> 6] = m; wsv[tid >> 6] = s; }
    __syncthreads();
    if (tid == 0) {
        float M = wm[0], S = wsv[0];
#pragma unroll
        for (int w2 = 1; w2 < 4; ++w2) sm_merge(M, S, wm[w2], wsv[w2]);
        total_s = M + logf(S);
    }
    __syncthreads();
    const float t = total_s;
    for (int v = blockIdx.x * 256 + tid; v < V; v += NB_FINAL * 256)
        out[v] -= t;
}

extern "C" void kernel_launch(void* const* d_in, const int* in_sizes, int n_in,
                              void* d_out, int out_size, void* d_ws, size_t ws_size,
                              hipStream_t stream) {
    const int*   ids    = (const int*)  d_in[0];   // i32 (or LE-i64 low word)
    const float* hidden = (const float*)d_in[1];
    const float* emb    = (const float*)d_in[2];
    const float* W_ih   = (const float*)d_in[3];
    const float* W_hh   = (const float*)d_in[4];
    const float* b_ih   = (const float*)d_in[5];
    const float* b_hh   = (const float*)d_in[6];
    const float* W_out  = (const float*)d_in[7];
    const float* b_out  = (const float*)d_in[8];

    float* out = (float*)d_out;        // [0..V) logp, [V..V+H) hidden_out

    float* ws   = (float*)d_ws;
    float* hnew = ws;                  // H
    float* pmax = ws + H;              // NB_TILES (covers fallback; fused uses NB)
    float* psum = pmax + NB_TILES;     // NB_TILES

    void* args[] = { (void*)&ids, (void*)&emb, (void*)&hidden,
                     (void*)&W_ih, (void*)&W_hh, (void*)&b_ih, (void*)&b_hh,
                     (void*)&W_out, (void*)&b_out,
                     (void*)&out, (void*)&hnew, (void*)&pmax, (void*)&psum };

    hipError_t err = hipLaunchCooperativeKernel(
        (const void*)decoder_fused, dim3(NB), dim3(256), args, 0, stream);

    if (err != hipSuccess) {
        // deterministic fallback: proven 3-kernel chain
        gru_fused_kernel<<<H, 256, 0, stream>>>(ids, emb, hidden, W_ih, W_hh,
                                                b_ih, b_hh, hnew, out + V);
        logits_kernel<<<NB_TILES, 256, 0, stream>>>(hnew, W_out, b_out, out,
                                                    pmax, psum);
        finalize_kernel<<<NB_FINAL, 256, 0, stream>>>(pmax, psum, out);
    }
}

// Round 4
// 51.360 us; speedup vs baseline: 4.6114x; 4.6114x over previous
//
#include <hip/hip_runtime.h>
#include <math.h>

#define H 1024
#define V 50257
#define NB_TILES 3142    // ceil(V / 16)
#define NB_FINAL 64

__device__ __forceinline__ float wave_reduce_sum(float v) {
#pragma unroll
    for (int off = 32; off >= 1; off >>= 1)
        v += __shfl_xor(v, off, 64);
    return v;
}

// online softmax merge: (m,s) <- merge((m,s),(mi,si))
__device__ __forceinline__ void sm_merge(float& m, float& s, float mi, float si) {
    if (mi > m) {
        s = s * expf(m - mi) + si;   // m==-inf, s==0 -> si
        m = mi;
    } else if (si > 0.f) {
        s += si * expf(mi - m);
    }
}

// K1: fused gates + GRU combine. One block per hidden index j (1024 blocks,
// 256 threads; each thread owns one float4 chunk of the k dimension).
// All 6 weight loads issued back-to-back for MLP before any FMA.
__global__ __launch_bounds__(256) void gru_fused_kernel(
    const int* __restrict__ ids, const float* __restrict__ emb,
    const float* __restrict__ hidden,
    const float* __restrict__ W_ih, const float* __restrict__ W_hh,
    const float* __restrict__ b_ih, const float* __restrict__ b_hh,
    float* __restrict__ hnew, float* __restrict__ out_hidden)
{
    const int j = blockIdx.x;
    const int t = threadIdx.x;
    const int wave = t >> 6;
    const int lane = t & 63;

    const int id = ids[0];

    // batch ALL loads first (8 outstanding 16B loads per thread)
    float4 x4 = ((const float4*)(emb + (size_t)id * H))[t];
    const float4 h4 = ((const float4*)hidden)[t];
    float4 wi[3], wh[3];
#pragma unroll
    for (int g = 0; g < 3; ++g) {
        wi[g] = ((const float4*)(W_ih + ((size_t)g * H + j) * H))[t];
        wh[g] = ((const float4*)(W_hh + ((size_t)g * H + j) * H))[t];
    }

    x4.x = fmaxf(x4.x, 0.f); x4.y = fmaxf(x4.y, 0.f);
    x4.z = fmaxf(x4.z, 0.f); x4.w = fmaxf(x4.w, 0.f);

    float acc[6];
#pragma unroll
    for (int g = 0; g < 3; ++g) {
        acc[2*g]   = wi[g].x * x4.x + wi[g].y * x4.y + wi[g].z * x4.z + wi[g].w * x4.w;
        acc[2*g+1] = wh[g].x * h4.x + wh[g].y * h4.y + wh[g].z * h4.z + wh[g].w * h4.w;
    }
#pragma unroll
    for (int g = 0; g < 6; ++g) acc[g] = wave_reduce_sum(acc[g]);

    __shared__ float red[4][6];
    if (lane == 0) {
#pragma unroll
        for (int g = 0; g < 6; ++g) red[wave][g] = acc[g];
    }
    __syncthreads();
    if (t == 0) {
        float tt[6];
#pragma unroll
        for (int g = 0; g < 6; ++g)
            tt[g] = red[0][g] + red[1][g] + red[2][g] + red[3][g];
        const float ir  = tt[0] + b_ih[j],        hr_ = tt[1] + b_hh[j];
        const float iz  = tt[2] + b_ih[H + j],    hz  = tt[3] + b_hh[H + j];
        const float in_ = tt[4] + b_ih[2*H + j],  hn  = tt[5] + b_hh[2*H + j];
        const float r = 1.f / (1.f + expf(-(ir + hr_)));
        const float z = 1.f / (1.f + expf(-(iz + hz)));
        const float n = tanhf(in_ + r * hn);
        const float h = hidden[j];
        const float o = (1.f - z) * n + z * h;
        hnew[j] = o;
        out_hidden[j] = o;
    }
}

// K2: logits + per-block online-softmax partials.
// 4 waves/block, 4 rows/wave = 16 rows/block. All 16 W_out float4 loads are
// issued into named registers BEFORE any FMA -> 16 outstanding loads/wave
// (the round-3 profile showed VGPR=28, i.e. ~1-2 in flight: latency-bound).
__global__ __launch_bounds__(256) void logits_kernel(
    const float* __restrict__ hnew, const float* __restrict__ W_out,
    const float* __restrict__ b_out, float* __restrict__ logits,
    float* __restrict__ pmax, float* __restrict__ psum)
{
    __shared__ float wm[4], wsv[4];
    const int wave = threadIdx.x >> 6;
    const int lane = threadIdx.x & 63;
    const int base = blockIdx.x * 16 + wave * 4;

    float4 hreg[4];
#pragma unroll
    for (int it = 0; it < 4; ++it)
        hreg[it] = ((const float4*)hnew)[it * 64 + lane];

    float m = -INFINITY, s = 0.f;

    if (base + 3 < V) {                       // fast path: full 4-row group
        float4 wreg[4][4];
#pragma unroll
        for (int r = 0; r < 4; ++r) {
            const float4* w = (const float4*)(W_out + (size_t)(base + r) * H);
#pragma unroll
            for (int it = 0; it < 4; ++it)
                wreg[r][it] = w[it * 64 + lane];
        }
        float acc[4];
#pragma unroll
        for (int r = 0; r < 4; ++r) {
            acc[r] = 0.f;
#pragma unroll
            for (int it = 0; it < 4; ++it)
                acc[r] += wreg[r][it].x * hreg[it].x + wreg[r][it].y * hreg[it].y
                        + wreg[r][it].z * hreg[it].z + wreg[r][it].w * hreg[it].w;
        }
#pragma unroll
        for (int r = 0; r < 4; ++r) acc[r] = wave_reduce_sum(acc[r]);
        if (lane == 0) {
#pragma unroll
            for (int r = 0; r < 4; ++r) {
                const float logit = acc[r] + b_out[base + r];
                logits[base + r] = logit;
                sm_merge(m, s, logit, 1.f);
            }
        }
    } else {                                  // tail (last block only)
        for (int r = 0; r < 4; ++r) {
            const int row = base + r;
            if (row >= V) break;              // wave-uniform
            const float4* w = (const float4*)(W_out + (size_t)row * H);
            float acc = 0.f;
#pragma unroll
            for (int it = 0; it < 4; ++it) {
                const float4 w4 = w[it * 64 + lane];
                acc += w4.x * hreg[it].x + w4.y * hreg[it].y
                     + w4.z * hreg[it].z + w4.w * hreg[it].w;
            }
            acc = wave_reduce_sum(acc);
            if (lane == 0) {
                const float logit = acc + b_out[row];
                logits[row] = logit;
                sm_merge(m, s, logit, 1.f);
            }
        }
    }

    if (lane == 0) { wm[wave] = m; wsv[wave] = s; }
    __syncthreads();
    if (threadIdx.x == 0) {
        float M = wm[0], S = wsv[0];
#pragma unroll
        for (int w2 = 1; w2 < 4; ++w2) sm_merge(M, S, wm[w2], wsv[w2]);
        pmax[blockIdx.x] = M;
        psum[blockIdx.x] = S;
    }
}

// K3: fused final reduce + logp. Every block deterministically merges all
// NB_TILES partials in identical order (bit-identical total), then
// grid-strides the in-place subtract over d_out[0..V).
__global__ __launch_bounds__(256) void finalize_kernel(
    const float* __restrict__ pmax, const float* __restrict__ psum,
    float* __restrict__ out)
{
    __shared__ float wm[4], wsv[4];
    __shared__ float total_s;
    const int tid = threadIdx.x;

    float m = -INFINITY, s = 0.f;
    for (int i = tid; i < NB_TILES; i += 256)
        sm_merge(m, s, pmax[i], psum[i]);
#pragma unroll
    for (int off = 32; off >= 1; off >>= 1) {
        const float mo = __shfl_xor(m, off, 64);
        const float so = __shfl_xor(s, off, 64);
        sm_merge(m, s, mo, so);
    }
    if ((tid & 63) == 0) { wm[tid >> 6] = m; wsv[tid >> 6] = s; }
    __syncthreads();
    if (tid == 0) {
        float M = wm[0], S = wsv[0];
#pragma unroll
        for (int w2 = 1; w2 < 4; ++w2) sm_merge(M, S, wm[w2], wsv[w2]);
        total_s = M + logf(S);
    }
    __syncthreads();
    const float t = total_s;
    for (int v = blockIdx.x * 256 + tid; v < V; v += NB_FINAL * 256)
        out[v] -= t;
}

extern "C" void kernel_launch(void* const* d_in, const int* in_sizes, int n_in,
                              void* d_out, int out_size, void* d_ws, size_t ws_size,
                              hipStream_t stream) {
    const int*   ids    = (const int*)  d_in[0];   // i32 (or LE-i64 low word)
    const float* hidden = (const float*)d_in[1];
    const float* emb    = (const float*)d_in[2];
    const float* W_ih   = (const float*)d_in[3];
    const float* W_hh   = (const float*)d_in[4];
    const float* b_ih   = (const float*)d_in[5];
    const float* b_hh   = (const float*)d_in[6];
    const float* W_out  = (const float*)d_in[7];
    const float* b_out  = (const float*)d_in[8];

    float* out = (float*)d_out;        // [0..V) logp, [V..V+H) hidden_out

    float* ws   = (float*)d_ws;
    float* hnew = ws;                  // H
    float* pmax = ws + H;              // NB_TILES
    float* psum = pmax + NB_TILES;     // NB_TILES

    gru_fused_kernel<<<H, 256, 0, stream>>>(ids, emb, hidden, W_ih, W_hh,
                                            b_ih, b_hh, hnew, out + V);
    logits_kernel<<<NB_TILES, 256, 0, stream>>>(hnew, W_out, b_out, out,
                                                pmax, psum);
    finalize_kernel<<<NB_FINAL, 256, 0, stream>>>(pmax, psum, out);
}